// Round 5
// baseline (145.538 us; speedup 1.0000x reference)
//
#include <hip/hip_runtime.h>
#include <hip/hip_bf16.h>
#include <stdint.h>

#define SDIM 2048
#define BDIM 8
#define FDIM 512
constexpr float ALPHA = 0.2f;

typedef __attribute__((ext_vector_type(8))) short bf16x8;
typedef __attribute__((ext_vector_type(4))) float f32x4;

__device__ __forceinline__ unsigned short f2bf(float x) {
  __hip_bfloat16 h = __float2bfloat16(x);
  return *reinterpret_cast<unsigned short*>(&h);
}

__device__ __forceinline__ void gload_lds16(const void* g, void* l) {
  __builtin_amdgcn_global_load_lds(
      (const __attribute__((address_space(1))) unsigned int*)(uintptr_t)g,
      (__attribute__((address_space(3))) unsigned int*)(uintptr_t)l,
      16, 0, 0);
}

// Barrier that drains ONLY LDS ops (ds_write visibility) — leaves global loads
// in flight across the barrier.
__device__ __forceinline__ void barrier_lgkm() {
  asm volatile("s_waitcnt lgkmcnt(0)" ::: "memory");
  __builtin_amdgcn_sched_barrier(0);
  __builtin_amdgcn_s_barrier();
}

// ---------------- K0: wa1/wa2 = W @ a halves (fp32), WT = bf16(W^T) ----------------
__global__ void k0_prep(const float* __restrict__ W, const float* __restrict__ a,
                        float* __restrict__ wa, __hip_bfloat16* __restrict__ WT) {
  int i = blockIdx.x;            // 512 rows of W
  int lane = threadIdx.x;        // 64
  float s1 = 0.f, s2 = 0.f;
  for (int o = lane; o < FDIM; o += 64) {
    float w = W[i * FDIM + o];
    s1 += w * a[o];
    s2 += w * a[FDIM + o];
    WT[o * FDIM + i] = __float2bfloat16(w);
  }
  #pragma unroll
  for (int off = 32; off > 0; off >>= 1) {
    s1 += __shfl_down(s1, off);
    s2 += __shfl_down(s2, off);
  }
  if (lane == 0) { wa[i] = s1; wa[FDIM + i] = s2; }
}

// ---------------- K1: per-row Wh1/Wh2 (fp32) + H -> bf16 ----------------
__global__ __launch_bounds__(256) void k1_rows(const float* __restrict__ H,
                                               const float* __restrict__ wa,
                                               float* __restrict__ Wh1, float* __restrict__ Wh2,
                                               __hip_bfloat16* __restrict__ Hb) {
  int wid = threadIdx.x >> 6, lane = threadIdx.x & 63;
  long r = (long)blockIdx.x * 4 + wid;          // 0..16383
  const float* hr = H + r * FDIM;
  float4 v0 = ((const float4*)hr)[lane];
  float4 v1 = ((const float4*)hr)[lane + 64];
  float4 wa10 = ((const float4*)wa)[lane];
  float4 wa11 = ((const float4*)wa)[lane + 64];
  float4 wa20 = ((const float4*)(wa + FDIM))[lane];
  float4 wa21 = ((const float4*)(wa + FDIM))[lane + 64];
  float s1 = v0.x*wa10.x + v0.y*wa10.y + v0.z*wa10.z + v0.w*wa10.w
           + v1.x*wa11.x + v1.y*wa11.y + v1.z*wa11.z + v1.w*wa11.w;
  float s2 = v0.x*wa20.x + v0.y*wa20.y + v0.z*wa20.z + v0.w*wa20.w
           + v1.x*wa21.x + v1.y*wa21.y + v1.z*wa21.z + v1.w*wa21.w;
  ushort4 u0 = { f2bf(v0.x), f2bf(v0.y), f2bf(v0.z), f2bf(v0.w) };
  ushort4 u1 = { f2bf(v1.x), f2bf(v1.y), f2bf(v1.z), f2bf(v1.w) };
  ushort4* hb = (ushort4*)(Hb + r * FDIM);
  hb[lane] = u0;
  hb[lane + 64] = u1;
  #pragma unroll
  for (int off = 32; off > 0; off >>= 1) {
    s1 += __shfl_down(s1, off);
    s2 += __shfl_down(s2, off);
  }
  if (lane == 0) { Wh1[r] = s1; Wh2[r] = s2; }
}

// ---------------- K2: partial column sums Z[b,t] over s-chunks ----------------
__global__ __launch_bounds__(256) void k2_z(const float* __restrict__ adj,
                                            const float* __restrict__ Wh1,
                                            const float* __restrict__ Wh2,
                                            float* __restrict__ Zp) {
  int t = blockIdx.x * 256 + threadIdx.x;  // grid.x = 8
  int b = blockIdx.y;                      // 8
  int c = blockIdx.z;                      // 32 chunks of 64 s each
  float w2 = Wh2[b * SDIM + t];
  const float* arow = adj + ((long)b * SDIM + c * 64) * SDIM + t;
  const float* w1p = Wh1 + b * SDIM + c * 64;
  float z = 0.f;
  #pragma unroll 8
  for (int s = 0; s < 64; ++s) {
    float av = arow[(long)s * SDIM];
    float e = w1p[s] + w2;
    e = e > 0.f ? e : ALPHA * e;
    float p = __expf(e);
    z += (av > 0.5f) ? p : 0.f;
  }
  Zp[(b * 32 + c) * SDIM + t] = z;
}

// ---------------- K2b: rZ = 1/sum(partials) ----------------
__global__ void k2b_rz(const float* __restrict__ Zp, float* __restrict__ rZ) {
  int idx = blockIdx.x * 256 + threadIdx.x;  // 16384
  int b = idx >> 11, t = idx & 2047;
  float z = 0.f;
  #pragma unroll
  for (int c = 0; c < 32; ++c) z += Zp[(b * 32 + c) * SDIM + t];
  rZ[idx] = 1.0f / z;
}

// ---------------- K3: V'^T[b][o][t] = bf16( (W^T @ H_b^T)[o][t] * rZ[b,t] ) ----------------
__global__ __launch_bounds__(256) void k3_gemm(const __hip_bfloat16* __restrict__ WTm,
                                               const __hip_bfloat16* __restrict__ Hb,
                                               const float* __restrict__ rZ,
                                               __hip_bfloat16* __restrict__ VT) {
  __shared__ __align__(16) __hip_bfloat16 Asm[2][128 * 32];
  __shared__ __align__(16) __hip_bfloat16 Bsm[2][128 * 32];
  const int o0 = blockIdx.x * 128;
  const int t0 = blockIdx.y * 128;
  const int b = blockIdx.z;
  const int tid = threadIdx.x;
  const int w = tid >> 6, lane = tid & 63;
  const int wm = w >> 1, wn = w & 1;
  const int fr = lane & 15, fq = lane >> 4;
  const int lr = lane >> 2, lb = (lane & 3) * 16;

  const __hip_bfloat16* Abase = WTm + (long)o0 * FDIM;
  const __hip_bfloat16* Bbase = Hb + ((long)b * SDIM + t0) * FDIM;

  f32x4 acc[4][4] = {};

  auto stage = [&](int kk, int buf) {
    #pragma unroll
    for (int g = 0; g < 2; ++g) {
      int rbase = g * 64 + w * 16;
      int row = rbase + lr;
      gload_lds16((const char*)(Abase + (long)row * FDIM + kk * 32) + lb,
                  (char*)&Asm[buf][0] + rbase * 64);
      gload_lds16((const char*)(Bbase + (long)row * FDIM + kk * 32) + lb,
                  (char*)&Bsm[buf][0] + rbase * 64);
    }
  };

  stage(0, 0);
  __syncthreads();
  for (int kk = 0; kk < 16; ++kk) {
    int cur = kk & 1;
    if (kk < 15) stage(kk + 1, cur ^ 1);
    bf16x8 af[4], bf_[4];
    #pragma unroll
    for (int mf = 0; mf < 4; ++mf)
      af[mf] = *(const bf16x8*)((const char*)&Asm[cur][0] + (wm * 64 + mf * 16 + fr) * 64 + fq * 16);
    #pragma unroll
    for (int nf = 0; nf < 4; ++nf)
      bf_[nf] = *(const bf16x8*)((const char*)&Bsm[cur][0] + (wn * 64 + nf * 16 + fr) * 64 + fq * 16);
    #pragma unroll
    for (int mf = 0; mf < 4; ++mf)
      #pragma unroll
      for (int nf = 0; nf < 4; ++nf)
        acc[mf][nf] = __builtin_amdgcn_mfma_f32_16x16x32_bf16(af[mf], bf_[nf], acc[mf][nf], 0, 0, 0);
    __syncthreads();
  }

  #pragma unroll
  for (int nf = 0; nf < 4; ++nf) {
    int t = t0 + wn * 64 + nf * 16 + fr;
    float rz = rZ[b * SDIM + t];
    #pragma unroll
    for (int mf = 0; mf < 4; ++mf) {
      #pragma unroll
      for (int r = 0; r < 4; ++r) {
        int o = o0 + wm * 64 + mf * 16 + fq * 4 + r;
        VT[((long)(b * FDIM + o)) * SDIM + t] = __float2bfloat16(acc[mf][nf][r] * rz);
      }
    }
  }
}

// ---------------- K4 v5: out = elu( P @ V' ) ----------------
// Register-budget-aware pipeline:
//   - V' (L2-resident): single-stage regs, loaded at TOP of the consuming phase
//     (~300cyc cover from pa ds_reads; counted vmcnt wait).
//   - adjacency (HBM-class): 2-phase register ping-pong (only 32 VGPRs).
//   - per-phase barrier drains lgkmcnt only; global loads stay in flight.
__global__ __launch_bounds__(256, 2) void k4_pv(const float* __restrict__ adj,
                                                const float* __restrict__ Wh1,
                                                const float* __restrict__ Wh2,
                                                const __hip_bfloat16* __restrict__ VT,
                                                float* __restrict__ out) {
  constexpr int PROW = 72;  // 144 B row stride: b128 reads/writes at 8-access bank floor
  __shared__ __align__(16) __hip_bfloat16 Psm[2][64 * PROW];  // 18.4 KB
  __shared__ __align__(16) float w2l[SDIM];                   // 8 KB
  const int b  = blockIdx.x;        // 8
  const int s0 = blockIdx.y * 64;   // 32
  const int ob = blockIdx.z * 256;  // 2
  const int tid = threadIdx.x;
  const int w = tid >> 6, lane = tid & 63;
  const int fr = lane & 15, fq = lane >> 4;
  const int sl = tid >> 2, oct = tid & 3;   // P-build: row sl (0..63), 16-t chunk oct

  // stage Wh2[b] into LDS
  {
    const float4* src = (const float4*)(Wh2 + (long)b * SDIM);
    float4* dst = (float4*)w2l;
    dst[tid] = src[tid];
    dst[tid + 256] = src[tid + 256];
  }
  const float w1 = Wh1[b * SDIM + s0 + sl];
  const float* adjRow = adj + ((long)b * SDIM + s0 + sl) * SDIM;
  const __hip_bfloat16* vbase = VT + ((long)(b * FDIM + ob + w * 64 + fr)) * SDIM;

  f32x4 acc[4][4] = {};
  bf16x8 vV[8];              // single-stage V frags [nf*2+ks]  (32 VGPRs)
  float4 aA[4], aB[4];       // adjacency 16 floats, two pipeline stages (32 VGPRs)

  auto loadV = [&](int p) {
    #pragma unroll
    for (int nf = 0; nf < 4; ++nf)
      #pragma unroll
      for (int ks = 0; ks < 2; ++ks)
        vV[nf * 2 + ks] = *(const bf16x8*)(vbase + (long)nf * 16 * SDIM + p * 64 + ks * 32 + fq * 8);
  };
  auto loadAdj = [&](int p, float4 (&ar)[4]) {
    const float* ap = adjRow + p * 64 + oct * 16;
    ar[0] = *(const float4*)(ap);
    ar[1] = *(const float4*)(ap + 4);
    ar[2] = *(const float4*)(ap + 8);
    ar[3] = *(const float4*)(ap + 12);
  };
  auto build = [&](int p, int buf, const float4 (&ar)[4]) {
    const int tb = p * 64 + oct * 16;
    float4 ww0 = *(const float4*)(w2l + tb);
    float4 ww1 = *(const float4*)(w2l + tb + 4);
    float4 ww2 = *(const float4*)(w2l + tb + 8);
    float4 ww3 = *(const float4*)(w2l + tb + 12);
    float aa[16] = {ar[0].x, ar[0].y, ar[0].z, ar[0].w, ar[1].x, ar[1].y, ar[1].z, ar[1].w,
                    ar[2].x, ar[2].y, ar[2].z, ar[2].w, ar[3].x, ar[3].y, ar[3].z, ar[3].w};
    float wwv[16] = {ww0.x, ww0.y, ww0.z, ww0.w, ww1.x, ww1.y, ww1.z, ww1.w,
                     ww2.x, ww2.y, ww2.z, ww2.w, ww3.x, ww3.y, ww3.z, ww3.w};
    bf16x8 pv0, pv1;
    #pragma unroll
    for (int i = 0; i < 16; ++i) {
      float e = w1 + wwv[i];
      e = fmaxf(e, ALPHA * e);           // leaky relu, 0<alpha<1
      float pr = (aa[i] > 0.5f) ? __expf(e) : 0.f;
      unsigned short u = f2bf(pr);
      if (i < 8) pv0[i] = (short)u; else pv1[i - 8] = (short)u;
    }
    *(bf16x8*)(&Psm[buf][sl * PROW + oct * 16]) = pv0;
    *(bf16x8*)(&Psm[buf][sl * PROW + oct * 16 + 8]) = pv1;
  };

  // prologue (one-time full barriers are fine)
  float4 aT[4];
  loadAdj(0, aT);
  loadAdj(1, aA);
  __syncthreads();            // w2l ready
  build(0, 0, aT);
  __syncthreads();            // Psm[0] ready

  auto body = [&](int p, float4 (&acur)[4], float4 (&anxt)[4]) {
    const int cur = p & 1;
    loadV(p);                                // same-phase V (L2 ~300cyc, covered by pa reads)
    if (p + 2 < 32) loadAdj(p + 2, anxt);    // 2-phase-ahead adjacency (HBM-class)
    bf16x8 pa[4][2];
    #pragma unroll
    for (int mf = 0; mf < 4; ++mf)
      #pragma unroll
      for (int ks = 0; ks < 2; ++ks)
        pa[mf][ks] = *(const bf16x8*)(&Psm[cur][(mf * 16 + fr) * PROW + ks * 32 + fq * 8]);
    #pragma unroll
    for (int mf = 0; mf < 4; ++mf)
      #pragma unroll
      for (int nf = 0; nf < 4; ++nf)
        #pragma unroll
        for (int ks = 0; ks < 2; ++ks)
          acc[mf][nf] = __builtin_amdgcn_mfma_f32_16x16x32_bf16(pa[mf][ks], vV[nf * 2 + ks],
                                                                acc[mf][nf], 0, 0, 0);
    if (p + 1 < 32) build(p + 1, cur ^ 1, acur);  // adjacency issued 2 phases ago
    barrier_lgkm();            // LDS-only drain: global prefetches survive
  };

  for (int p = 0; p < 32; p += 2) {
    body(p, aA, aB);
    body(p + 1, aB, aA);
  }

  // epilogue: ELU + store
  float* orow = out + ((long)b * SDIM + s0) * FDIM + ob + w * 64;
  #pragma unroll
  for (int mf = 0; mf < 4; ++mf) {
    #pragma unroll
    for (int nf = 0; nf < 4; ++nf) {
      #pragma unroll
      for (int r = 0; r < 4; ++r) {
        int s = mf * 16 + fq * 4 + r;
        int o = nf * 16 + fr;
        float x = acc[mf][nf][r];
        x = x > 0.f ? x : (__expf(x) - 1.f);
        orow[(long)s * FDIM + o] = x;
      }
    }
  }
}

extern "C" void kernel_launch(void* const* d_in, const int* in_sizes, int n_in,
                              void* d_out, int out_size, void* d_ws, size_t ws_size,
                              hipStream_t stream) {
  const float* H   = (const float*)d_in[0];   // [8,2048,512]
  const float* adj = (const float*)d_in[1];   // [8,2048,2048]
  const float* W   = (const float*)d_in[2];   // [512,512]
  const float* a   = (const float*)d_in[3];   // [1024,1]
  float* out = (float*)d_out;
  char* ws = (char*)d_ws;

  __hip_bfloat16* VT  = (__hip_bfloat16*)(ws + 0);         // 16 MB  [8][512][2048]
  __hip_bfloat16* Hb  = (__hip_bfloat16*)(ws + 16777216);  // 16 MB  [16384][512]
  __hip_bfloat16* WT  = (__hip_bfloat16*)(ws + 33554432);  // 512 KB [512][512]
  float* wa  = (float*)(ws + 34078720);                    // 4 KB
  float* Wh1 = (float*)(ws + 34082816);                    // 64 KB
  float* Wh2 = (float*)(ws + 34148352);                    // 64 KB
  float* rZ  = (float*)(ws + 34213888);                    // 64 KB
  float* Zp  = (float*)(ws + 34279424);                    // 2 MB

  hipLaunchKernelGGL(k0_prep, dim3(512), dim3(64), 0, stream, W, a, wa, WT);
  hipLaunchKernelGGL(k1_rows, dim3(4096), dim3(256), 0, stream, H, wa, Wh1, Wh2, Hb);
  hipLaunchKernelGGL(k2_z, dim3(8, 8, 32), dim3(256), 0, stream, adj, Wh1, Wh2, Zp);
  hipLaunchKernelGGL(k2b_rz, dim3(64), dim3(256), 0, stream, Zp, rZ);
  hipLaunchKernelGGL(k3_gemm, dim3(4, 16, 8), dim3(256), 0, stream, WT, Hb, rZ, VT);
  hipLaunchKernelGGL(k4_pv, dim3(8, 32, 2), dim3(256), 0, stream, adj, Wh1, Wh2, VT, out);
}

// Round 6
// 125.376 us; speedup vs baseline: 1.1608x; 1.1608x over previous
//
#include <hip/hip_runtime.h>
#include <hip/hip_bf16.h>
#include <stdint.h>

#define SDIM 2048
#define BDIM 8
#define FDIM 512
constexpr float ALPHA = 0.2f;

typedef __attribute__((ext_vector_type(8))) short bf16x8;
typedef __attribute__((ext_vector_type(4))) float f32x4;

__device__ __forceinline__ unsigned short f2bf(float x) {
  __hip_bfloat16 h = __float2bfloat16(x);
  return *reinterpret_cast<unsigned short*>(&h);
}

__device__ __forceinline__ void gload_lds16(const void* g, void* l) {
  __builtin_amdgcn_global_load_lds(
      (const __attribute__((address_space(1))) unsigned int*)(uintptr_t)g,
      (__attribute__((address_space(3))) unsigned int*)(uintptr_t)l,
      16, 0, 0);
}

// ---------------- K0: wa1/wa2 = W @ a halves (fp32), WT = bf16(W^T) ----------------
__global__ void k0_prep(const float* __restrict__ W, const float* __restrict__ a,
                        float* __restrict__ wa, __hip_bfloat16* __restrict__ WT) {
  int i = blockIdx.x;            // 512 rows of W
  int lane = threadIdx.x;        // 64
  float s1 = 0.f, s2 = 0.f;
  for (int o = lane; o < FDIM; o += 64) {
    float w = W[i * FDIM + o];
    s1 += w * a[o];
    s2 += w * a[FDIM + o];
    WT[o * FDIM + i] = __float2bfloat16(w);
  }
  #pragma unroll
  for (int off = 32; off > 0; off >>= 1) {
    s1 += __shfl_down(s1, off);
    s2 += __shfl_down(s2, off);
  }
  if (lane == 0) { wa[i] = s1; wa[FDIM + i] = s2; }
}

// ---------------- K1: per-row Wh1/Wh2 (fp32) + H -> bf16 ----------------
__global__ __launch_bounds__(256) void k1_rows(const float* __restrict__ H,
                                               const float* __restrict__ wa,
                                               float* __restrict__ Wh1, float* __restrict__ Wh2,
                                               __hip_bfloat16* __restrict__ Hb) {
  int wid = threadIdx.x >> 6, lane = threadIdx.x & 63;
  long r = (long)blockIdx.x * 4 + wid;          // 0..16383
  const float* hr = H + r * FDIM;
  float4 v0 = ((const float4*)hr)[lane];
  float4 v1 = ((const float4*)hr)[lane + 64];
  float4 wa10 = ((const float4*)wa)[lane];
  float4 wa11 = ((const float4*)wa)[lane + 64];
  float4 wa20 = ((const float4*)(wa + FDIM))[lane];
  float4 wa21 = ((const float4*)(wa + FDIM))[lane + 64];
  float s1 = v0.x*wa10.x + v0.y*wa10.y + v0.z*wa10.z + v0.w*wa10.w
           + v1.x*wa11.x + v1.y*wa11.y + v1.z*wa11.z + v1.w*wa11.w;
  float s2 = v0.x*wa20.x + v0.y*wa20.y + v0.z*wa20.z + v0.w*wa20.w
           + v1.x*wa21.x + v1.y*wa21.y + v1.z*wa21.z + v1.w*wa21.w;
  ushort4 u0 = { f2bf(v0.x), f2bf(v0.y), f2bf(v0.z), f2bf(v0.w) };
  ushort4 u1 = { f2bf(v1.x), f2bf(v1.y), f2bf(v1.z), f2bf(v1.w) };
  ushort4* hb = (ushort4*)(Hb + r * FDIM);
  hb[lane] = u0;
  hb[lane + 64] = u1;
  #pragma unroll
  for (int off = 32; off > 0; off >>= 1) {
    s1 += __shfl_down(s1, off);
    s2 += __shfl_down(s2, off);
  }
  if (lane == 0) { Wh1[r] = s1; Wh2[r] = s2; }
}

// ---------------- K2: partial column sums Z[b,t] over s-chunks ----------------
__global__ __launch_bounds__(256) void k2_z(const float* __restrict__ adj,
                                            const float* __restrict__ Wh1,
                                            const float* __restrict__ Wh2,
                                            float* __restrict__ Zp) {
  int t = blockIdx.x * 256 + threadIdx.x;  // grid.x = 8
  int b = blockIdx.y;                      // 8
  int c = blockIdx.z;                      // 32 chunks of 64 s each
  float w2 = Wh2[b * SDIM + t];
  const float* arow = adj + ((long)b * SDIM + c * 64) * SDIM + t;
  const float* w1p = Wh1 + b * SDIM + c * 64;
  float z = 0.f;
  #pragma unroll 8
  for (int s = 0; s < 64; ++s) {
    float av = arow[(long)s * SDIM];
    float e = w1p[s] + w2;
    e = e > 0.f ? e : ALPHA * e;
    float p = __expf(e);
    z += (av > 0.5f) ? p : 0.f;
  }
  Zp[(b * 32 + c) * SDIM + t] = z;
}

// ---------------- K2b: rZ = 1/sum(partials) ----------------
__global__ void k2b_rz(const float* __restrict__ Zp, float* __restrict__ rZ) {
  int idx = blockIdx.x * 256 + threadIdx.x;  // 16384
  int b = idx >> 11, t = idx & 2047;
  float z = 0.f;
  #pragma unroll
  for (int c = 0; c < 32; ++c) z += Zp[(b * 32 + c) * SDIM + t];
  rZ[idx] = 1.0f / z;
}

// ---------------- K3: V'^T[b][o][t] = bf16( (W^T @ H_b^T)[o][t] * rZ[b,t] ) ----------------
__global__ __launch_bounds__(256) void k3_gemm(const __hip_bfloat16* __restrict__ WTm,
                                               const __hip_bfloat16* __restrict__ Hb,
                                               const float* __restrict__ rZ,
                                               __hip_bfloat16* __restrict__ VT) {
  __shared__ __align__(16) __hip_bfloat16 Asm[2][128 * 32];
  __shared__ __align__(16) __hip_bfloat16 Bsm[2][128 * 32];
  const int o0 = blockIdx.x * 128;
  const int t0 = blockIdx.y * 128;
  const int b = blockIdx.z;
  const int tid = threadIdx.x;
  const int w = tid >> 6, lane = tid & 63;
  const int wm = w >> 1, wn = w & 1;
  const int fr = lane & 15, fq = lane >> 4;
  const int lr = lane >> 2, lb = (lane & 3) * 16;

  const __hip_bfloat16* Abase = WTm + (long)o0 * FDIM;
  const __hip_bfloat16* Bbase = Hb + ((long)b * SDIM + t0) * FDIM;

  f32x4 acc[4][4] = {};

  auto stage = [&](int kk, int buf) {
    #pragma unroll
    for (int g = 0; g < 2; ++g) {
      int rbase = g * 64 + w * 16;
      int row = rbase + lr;
      gload_lds16((const char*)(Abase + (long)row * FDIM + kk * 32) + lb,
                  (char*)&Asm[buf][0] + rbase * 64);
      gload_lds16((const char*)(Bbase + (long)row * FDIM + kk * 32) + lb,
                  (char*)&Bsm[buf][0] + rbase * 64);
    }
  };

  stage(0, 0);
  __syncthreads();
  for (int kk = 0; kk < 16; ++kk) {
    int cur = kk & 1;
    if (kk < 15) stage(kk + 1, cur ^ 1);
    bf16x8 af[4], bf_[4];
    #pragma unroll
    for (int mf = 0; mf < 4; ++mf)
      af[mf] = *(const bf16x8*)((const char*)&Asm[cur][0] + (wm * 64 + mf * 16 + fr) * 64 + fq * 16);
    #pragma unroll
    for (int nf = 0; nf < 4; ++nf)
      bf_[nf] = *(const bf16x8*)((const char*)&Bsm[cur][0] + (wn * 64 + nf * 16 + fr) * 64 + fq * 16);
    #pragma unroll
    for (int mf = 0; mf < 4; ++mf)
      #pragma unroll
      for (int nf = 0; nf < 4; ++nf)
        acc[mf][nf] = __builtin_amdgcn_mfma_f32_16x16x32_bf16(af[mf], bf_[nf], acc[mf][nf], 0, 0, 0);
    __syncthreads();
  }

  #pragma unroll
  for (int nf = 0; nf < 4; ++nf) {
    int t = t0 + wn * 64 + nf * 16 + fr;
    float rz = rZ[b * SDIM + t];
    #pragma unroll
    for (int mf = 0; mf < 4; ++mf) {
      #pragma unroll
      for (int r = 0; r < 4; ++r) {
        int o = o0 + wm * 64 + mf * 16 + fq * 4 + r;
        VT[((long)(b * FDIM + o)) * SDIM + t] = __float2bfloat16(acc[mf][nf][r] * rz);
      }
    }
  }
}

// ---------------- K4 v6: out = elu( P @ V' ), ALL staging via global_load_lds ----------------
// Phase = 32 t (64 phases). Per phase per wave: 4 gload_lds (V, 1-ahead) +
// 2 gload_lds (adj, staged for build 3 phases later -> 2-phase cover) = 6 vmem.
// Barrier: s_waitcnt vmcnt(2) (adj stage stays in flight) + lgkmcnt(0) + s_barrier.
// build(p+1) runs in phase p: reads AdjSm ring slot (p+1)%3, writes Psm[(p+1)&1].
// Rotated chunk mapping (oct+sl)&3 puts all LDS access at the 32-bank floor.
__global__ __launch_bounds__(256, 2) void k4_pv(const float* __restrict__ adj,
                                                const float* __restrict__ Wh1,
                                                const float* __restrict__ Wh2,
                                                const __hip_bfloat16* __restrict__ VT,
                                                float* __restrict__ out) {
  __shared__ __align__(16) __hip_bfloat16 Vsm[2][256 * 32];  // 32 KB
  __shared__ __align__(16) float AdjSm[3][64 * 32];          // 24 KB
  __shared__ __align__(16) __hip_bfloat16 Psm[2][64 * 32];   // 8 KB
  __shared__ __align__(16) float w2l[SDIM];                  // 8 KB
  const int b  = blockIdx.x;        // 8  (linear id % 8 == b -> XCD pinning)
  const int s0 = blockIdx.y * 64;   // 32
  const int ob = blockIdx.z * 256;  // 2
  const int tid = threadIdx.x;
  const int w = tid >> 6, lane = tid & 63;
  const int fr = lane & 15, fq = lane >> 4;
  const int sl = tid >> 2, oct = tid & 3;
  const int chk = (oct + sl) & 3;   // rotated t-chunk: conflict-free adj/Psm access

  const float w1 = Wh1[b * SDIM + s0 + sl];
  const char* adjG = (const char*)(adj + ((long)b * SDIM + s0) * SDIM);
  const char* vtG  = (const char*)(VT + ((long)(b * FDIM + ob)) * SDIM);
  const char* w2G  = (const char*)(Wh2 + (long)b * SDIM);

  f32x4 acc[4][4] = {};

  auto stageV = [&](int p, int buf) {
    #pragma unroll
    for (int g = 0; g < 4; ++g) {
      int row = w * 64 + g * 16 + (lane >> 2);           // per-lane global row
      gload_lds16(vtG + ((long)row * SDIM + p * 32) * 2 + (lane & 3) * 16,
                  (char*)&Vsm[buf][0] + (w * 64 + g * 16) * 64);  // wave-uniform dest
    }
  };
  auto stageA = [&](int p, int slot) {
    #pragma unroll
    for (int g = 0; g < 2; ++g) {
      int row = w * 16 + g * 8 + (lane >> 3);
      gload_lds16(adjG + ((long)row * SDIM + p * 32) * 4 + (lane & 7) * 16,
                  (char*)&AdjSm[slot][0] + (w * 16 + g * 8) * 128);
    }
  };
  auto build = [&](int p, int pbuf, int slot) {   // build P for phase p
    const float* arow = &AdjSm[slot][sl * 32 + chk * 8];
    float4 a0 = *(const float4*)(arow);
    float4 a1 = *(const float4*)(arow + 4);
    const float* wrow = &w2l[p * 32 + chk * 8];
    float4 q0 = *(const float4*)(wrow);
    float4 q1 = *(const float4*)(wrow + 4);
    float aa[8] = {a0.x,a0.y,a0.z,a0.w,a1.x,a1.y,a1.z,a1.w};
    float qq[8] = {q0.x,q0.y,q0.z,q0.w,q1.x,q1.y,q1.z,q1.w};
    bf16x8 pv;
    #pragma unroll
    for (int i = 0; i < 8; ++i) {
      float e = w1 + qq[i];
      e = fmaxf(e, ALPHA * e);
      float pr = (aa[i] > 0.5f) ? __expf(e) : 0.f;
      pv[i] = (short)f2bf(pr);
    }
    *(bf16x8*)(&Psm[pbuf][sl * 32 + chk * 8]) = pv;
  };

  // ---- prologue ----
  #pragma unroll
  for (int g = 0; g < 2; ++g)
    gload_lds16(w2G + w * 2048 + g * 1024 + lane * 16,
                (char*)w2l + w * 2048 + g * 1024);
  stageA(0, 0);
  stageA(1, 1);
  stageV(0, 0);
  asm volatile("s_waitcnt vmcnt(0)" ::: "memory");
  __syncthreads();
  build(0, 0, 0);
  stageA(2, 2);                               // matches steady-state 3-ahead pattern
  asm volatile("s_waitcnt lgkmcnt(0)" ::: "memory");
  __builtin_amdgcn_sched_barrier(0);
  __builtin_amdgcn_s_barrier();

  // ---- main loop ----
  int slotS = 0;   // stage target at top of phase p: slot p%3
  int slotB = 1;   // build(p+1) reads slot (p+1)%3
  for (int p = 0; p < 64; ++p) {
    const int cur = p & 1;
    if (p <= 62) stageV(p + 1, cur ^ 1);
    if (p <= 60) stageA(p + 3, slotS);
    __builtin_amdgcn_sched_barrier(0);        // keep stage issues at phase top

    bf16x8 pa[4], vb[4];
    #pragma unroll
    for (int mf = 0; mf < 4; ++mf)
      pa[mf] = *(const bf16x8*)(&Psm[cur][(mf * 16 + fr) * 32 + fq * 8]);
    #pragma unroll
    for (int nf = 0; nf < 4; ++nf)
      vb[nf] = *(const bf16x8*)(&Vsm[cur][(w * 64 + nf * 16 + fr) * 32 + fq * 8]);
    __builtin_amdgcn_s_setprio(1);
    #pragma unroll
    for (int mf = 0; mf < 4; ++mf)
      #pragma unroll
      for (int nf = 0; nf < 4; ++nf)
        acc[mf][nf] = __builtin_amdgcn_mfma_f32_16x16x32_bf16(pa[mf], vb[nf], acc[mf][nf], 0, 0, 0);
    __builtin_amdgcn_s_setprio(0);

    if (p <= 62) build(p + 1, cur ^ 1, slotB);

    if (p <= 60) { asm volatile("s_waitcnt vmcnt(2)" ::: "memory"); }
    else         { asm volatile("s_waitcnt vmcnt(0)" ::: "memory"); }
    asm volatile("s_waitcnt lgkmcnt(0)" ::: "memory");
    __builtin_amdgcn_sched_barrier(0);
    __builtin_amdgcn_s_barrier();

    slotS = slotB;
    slotB = (slotB == 2) ? 0 : slotB + 1;
  }

  // ---- epilogue: ELU + store ----
  float* orow = out + ((long)b * SDIM + s0) * FDIM + ob + w * 64;
  #pragma unroll
  for (int mf = 0; mf < 4; ++mf) {
    #pragma unroll
    for (int nf = 0; nf < 4; ++nf) {
      #pragma unroll
      for (int r = 0; r < 4; ++r) {
        int s = mf * 16 + fq * 4 + r;
        int o = nf * 16 + fr;
        float x = acc[mf][nf][r];
        x = x > 0.f ? x : (__expf(x) - 1.f);
        orow[(long)s * FDIM + o] = x;
      }
    }
  }
}

extern "C" void kernel_launch(void* const* d_in, const int* in_sizes, int n_in,
                              void* d_out, int out_size, void* d_ws, size_t ws_size,
                              hipStream_t stream) {
  const float* H   = (const float*)d_in[0];   // [8,2048,512]
  const float* adj = (const float*)d_in[1];   // [8,2048,2048]
  const float* W   = (const float*)d_in[2];   // [512,512]
  const float* a   = (const float*)d_in[3];   // [1024,1]
  float* out = (float*)d_out;
  char* ws = (char*)d_ws;

  __hip_bfloat16* VT  = (__hip_bfloat16*)(ws + 0);         // 16 MB  [8][512][2048]
  __hip_bfloat16* Hb  = (__hip_bfloat16*)(ws + 16777216);  // 16 MB  [16384][512]
  __hip_bfloat16* WT  = (__hip_bfloat16*)(ws + 33554432);  // 512 KB [512][512]
  float* wa  = (float*)(ws + 34078720);                    // 4 KB
  float* Wh1 = (float*)(ws + 34082816);                    // 64 KB
  float* Wh2 = (float*)(ws + 34148352);                    // 64 KB
  float* rZ  = (float*)(ws + 34213888);                    // 64 KB
  float* Zp  = (float*)(ws + 34279424);                    // 2 MB

  hipLaunchKernelGGL(k0_prep, dim3(512), dim3(64), 0, stream, W, a, wa, WT);
  hipLaunchKernelGGL(k1_rows, dim3(4096), dim3(256), 0, stream, H, wa, Wh1, Wh2, Hb);
  hipLaunchKernelGGL(k2_z, dim3(8, 8, 32), dim3(256), 0, stream, adj, Wh1, Wh2, Zp);
  hipLaunchKernelGGL(k2b_rz, dim3(64), dim3(256), 0, stream, Zp, rZ);
  hipLaunchKernelGGL(k3_gemm, dim3(4, 16, 8), dim3(256), 0, stream, WT, Hb, rZ, VT);
  hipLaunchKernelGGL(k4_pv, dim3(8, 32, 2), dim3(256), 0, stream, adj, Wh1, Wh2, VT, out);
}